// Round 1
// baseline (654.769 us; speedup 1.0000x reference)
//
#include <hip/hip_runtime.h>

typedef unsigned short u16;
typedef unsigned int   u32;

#define NB     512
#define INC    256
#define NHEADS 8
#define HW     361
#define NPIX   184832      /* NB*HW */
#define NTOT   768
#define NWG_M  1444        /* NPIX/128 */
#define EPSBN  1e-5f

typedef __bf16 bf16x8 __attribute__((ext_vector_type(8)));
typedef float  f32x4  __attribute__((ext_vector_type(4)));

__device__ __forceinline__ u16 f2bf(float f) {
  u32 u = __float_as_uint(f);
  u += 0x7fffu + ((u >> 16) & 1u);          // round-to-nearest-even
  return (u16)(u >> 16);
}
__device__ __forceinline__ float bf2f(u16 v) {
  return __uint_as_float(((u32)v) << 16);
}

// ---------------- kernel 0: W -> bf16 [768][256] row-swizzled, bias, zero stats
__global__ __launch_bounds__(256) void k_prep(
    const float* __restrict__ Wq, const float* __restrict__ bq,
    const float* __restrict__ Wk, const float* __restrict__ bk,
    const float* __restrict__ Wv, const float* __restrict__ bv,
    u16* __restrict__ Wall, float* __restrict__ ball, float* __restrict__ stats) {
  const int n = blockIdx.x, t = threadIdx.x;
  const float* src; const float* bs; int r;
  if (n < 256)      { src = Wq; bs = bq; r = n; }
  else if (n < 512) { src = Wk; bs = bk; r = n - 256; }
  else              { src = Wv; bs = bv; r = n - 512; }
  float v = src[r * 256 + t];
  int byte = (t * 2) ^ ((n & 7) << 4);      // XOR swizzle, 16B granules (T2/G4)
  *(u16*)((char*)Wall + (size_t)n * 512 + byte) = f2bf(v);
  if (t == 0) ball[n] = bs[r];
  if (n == 0) { for (int i = t; i < 1536; i += 256) stats[i] = 0.f; }
}

// ---------------- kernel 0b: x [B][256][361] f32 -> xT [NPIX][256] bf16, row-swizzled
__global__ __launch_bounds__(384) void k_xt(const float* __restrict__ x, u16* __restrict__ xT) {
  const int bb = blockIdx.x, t = threadIdx.x;
  if (t >= HW) return;
  const size_t m = (size_t)bb * HW + t;
  const float* xp = x + (size_t)bb * INC * HW + t;
  char* dst = (char*)xT + m * 512;
  const int swz = ((int)m & 7) << 4;
  #pragma unroll 1
  for (int cc = 0; cc < INC; cc += 32) {
    __align__(16) u16 tmp[32];
    #pragma unroll
    for (int c = 0; c < 32; ++c) tmp[c] = f2bf(xp[(size_t)(cc + c) * HW]);
    #pragma unroll
    for (int p = 0; p < 4; ++p)
      *(uint4*)(dst + ((cc * 2 + p * 16) ^ swz)) = ((const uint4*)tmp)[p];
  }
}

// ---------------- kernel 1: QKV GEMM (M-tile 128, all 768 N, K=256) + stats epilogue
__global__ __launch_bounds__(256) void k_gemm(
    const u16* __restrict__ xT, const u16* __restrict__ Wall,
    const float* __restrict__ ball, u16* __restrict__ qkv, float* __restrict__ stats) {
  __shared__ u16 Al[128 * 256];                       // 64 KB, swizzled rows
  const int tid  = threadIdx.x;
  const int m0   = blockIdx.x * 128;
  {                                                   // stage A: contiguous 64 KB
    const uint4* src = (const uint4*)(xT + (size_t)m0 * 256);
    uint4* dst = (uint4*)Al;
    #pragma unroll
    for (int i = tid; i < 4096; i += 256) dst[i] = src[i];
  }
  __syncthreads();
  const int lane = tid & 63;
  const int w    = tid >> 6;
  const int wm   = w >> 1, wn = w & 1;
  const int l15  = lane & 15, kq = lane >> 4;
  const int swz  = (lane & 7) << 4;                   // row&7 == lane&7 for our rows
  const char* Alb = (const char*)Al;
  const char* Wb  = (const char*)Wall;

  #pragma unroll 1
  for (int nt = 0; nt < 6; ++nt) {
    f32x4 acc[4][4];
    #pragma unroll
    for (int i = 0; i < 4; ++i)
      #pragma unroll
      for (int j = 0; j < 4; ++j) acc[i][j] = (f32x4){0.f, 0.f, 0.f, 0.f};
    const int nbase = nt * 128 + wn * 64;
    #pragma unroll
    for (int ks = 0; ks < 8; ++ks) {
      const int kb = kq * 16 + ks * 64;
      bf16x8 av[4], bv[4];
      #pragma unroll
      for (int mi = 0; mi < 4; ++mi) {
        int r = wm * 64 + mi * 16 + l15;
        av[mi] = __builtin_bit_cast(bf16x8, *(const uint4*)(Alb + r * 512 + (kb ^ swz)));
      }
      #pragma unroll
      for (int ni = 0; ni < 4; ++ni) {
        int n = nbase + ni * 16 + l15;
        bv[ni] = __builtin_bit_cast(bf16x8, *(const uint4*)(Wb + (size_t)n * 512 + (kb ^ swz)));
      }
      #pragma unroll
      for (int mi = 0; mi < 4; ++mi)
        #pragma unroll
        for (int ni = 0; ni < 4; ++ni)
          acc[mi][ni] = __builtin_amdgcn_mfma_f32_16x16x32_bf16(av[mi], bv[ni], acc[mi][ni], 0, 0, 0);
    }
    // epilogue: bias, bf16 store, per-channel sum/sumsq
    #pragma unroll
    for (int ni = 0; ni < 4; ++ni) {
      const int n = nbase + ni * 16 + l15;
      const float bias = ball[n];
      float s = 0.f, sq = 0.f;
      #pragma unroll
      for (int mi = 0; mi < 4; ++mi) {
        const int rbase = m0 + wm * 64 + mi * 16 + kq * 4;
        #pragma unroll
        for (int j = 0; j < 4; ++j) {
          float v = acc[mi][ni][j] + bias;
          qkv[(size_t)(rbase + j) * NTOT + n] = f2bf(v);
          s += v; sq += v * v;
        }
      }
      s  += __shfl_down(s, 32);  sq += __shfl_down(sq, 32);
      s  += __shfl_down(s, 16);  sq += __shfl_down(sq, 16);
      if (kq == 0) {
        atomicAdd(&stats[n], s);
        atomicAdd(&stats[NTOT + n], sq);
      }
    }
  }
}

// ---------------- kernel 2: finalize BN -> s_all, t_all
__global__ void k_stats(const float* __restrict__ stats,
                        const float* __restrict__ gQ, const float* __restrict__ betaQ,
                        const float* __restrict__ gK, const float* __restrict__ betaK,
                        const float* __restrict__ gV, const float* __restrict__ betaV,
                        float* __restrict__ s_all, float* __restrict__ t_all) {
  const int n = threadIdx.x;
  if (n >= NTOT) return;
  const float invP = 1.f / (float)NPIX;
  float mean = stats[n] * invP;
  float var  = stats[NTOT + n] * invP - mean * mean;
  float g, be;
  if (n < 256)      { g = gQ[n];       be = betaQ[n]; }
  else if (n < 512) { g = gK[n - 256]; be = betaK[n - 256]; }
  else              { g = gV[n - 512]; be = betaV[n - 512]; }
  float s = g * rsqrtf(var + EPSBN);
  s_all[n] = s;
  t_all[n] = be - s * mean;
}

// ---------------- kernel 3: neighbor attention + softmax + ReLU + residual
__global__ __launch_bounds__(384) void k_attn(
    const u16* __restrict__ qkv, const float* __restrict__ s_all,
    const float* __restrict__ t_all, const float* __restrict__ x,
    float* __restrict__ out) {
  __shared__ u16   Kl[32][HW];
  __shared__ u16   Vl[32][HW];
  __shared__ float aL[4][HW];
  __shared__ float sl[96], tl[96];   // [0:32)=Q, [32:64)=K, [64:96)=V
  const int bb = blockIdx.x, h = blockIdx.y, tid = threadIdx.x;
  const size_t rowb = (size_t)bb * HW * NTOT;

  if (tid < 96) {
    int which = tid >> 5, c = tid & 31;
    int n = which * 256 + h * 32 + c;
    sl[tid] = s_all[n]; tl[tid] = t_all[n];
  }
  // stage raw K,V (bf16) into [c][px] LDS layout
  const u16* kvb = qkv + rowb + 256 + h * 32;
  for (int i = tid; i < HW * 8; i += 384) {
    int px = i >> 3, c4 = (i & 7) << 2;
    const u16* sp = kvb + (size_t)px * NTOT + c4;
    uint2 kk = *(const uint2*)sp;
    uint2 vv = *(const uint2*)(sp + 256);
    Kl[c4 + 0][px] = (u16)(kk.x & 0xffffu); Kl[c4 + 1][px] = (u16)(kk.x >> 16);
    Kl[c4 + 2][px] = (u16)(kk.y & 0xffffu); Kl[c4 + 3][px] = (u16)(kk.y >> 16);
    Vl[c4 + 0][px] = (u16)(vv.x & 0xffffu); Vl[c4 + 1][px] = (u16)(vv.x >> 16);
    Vl[c4 + 2][px] = (u16)(vv.y & 0xffffu); Vl[c4 + 3][px] = (u16)(vv.y >> 16);
  }
  __syncthreads();

  // phase 1: per-pixel logits + softmax
  if (tid < HW) {
    const int px = tid;
    const int yy = px / 19, xx = px % 19;
    float Qp[32];
    float Cterm = 0.f;
    const u16* qsrc = qkv + rowb + (size_t)px * NTOT + h * 32;
    #pragma unroll
    for (int c = 0; c < 32; c += 4) {
      uint2 qv = *(const uint2*)(qsrc + c);
      float q0 = bf2f((u16)(qv.x & 0xffffu));
      float q1 = bf2f((u16)(qv.x >> 16));
      float q2 = bf2f((u16)(qv.y & 0xffffu));
      float q3 = bf2f((u16)(qv.y >> 16));
      float qn;
      qn = sl[c+0]*q0 + tl[c+0]; Cterm += qn*tl[32+c+0]; Qp[c+0] = qn*sl[32+c+0];
      qn = sl[c+1]*q1 + tl[c+1]; Cterm += qn*tl[32+c+1]; Qp[c+1] = qn*sl[32+c+1];
      qn = sl[c+2]*q2 + tl[c+2]; Cterm += qn*tl[32+c+2]; Qp[c+2] = qn*sl[32+c+2];
      qn = sl[c+3]*q3 + tl[c+3]; Cterm += qn*tl[32+c+3]; Qp[c+3] = qn*sl[32+c+3];
    }
    const float rs = 0.17677669529663687f;   // 1/sqrt(32)
    Cterm *= rs;
    #pragma unroll
    for (int c = 0; c < 32; ++c) Qp[c] *= rs;

    const int  npx[4] = {px - 19, px + 19, px - 1, px + 1};
    const bool ib[4]  = {yy > 0, yy < 18, xx > 0, xx < 18};
    float lgt[4];
    #pragma unroll
    for (int d = 0; d < 4; ++d) {
      int pn = ib[d] ? npx[d] : px;            // clamp (predicated, no divergence)
      float s = 0.f;
      #pragma unroll
      for (int c = 0; c < 32; ++c) s += Qp[c] * bf2f(Kl[c][pn]);
      lgt[d] = ib[d] ? (s + Cterm) : 0.f;      // OOB neighbor => logit exactly 0
    }
    float mx = fmaxf(fmaxf(lgt[0], lgt[1]), fmaxf(lgt[2], lgt[3]));
    float e0 = __expf(lgt[0] - mx), e1 = __expf(lgt[1] - mx);
    float e2 = __expf(lgt[2] - mx), e3 = __expf(lgt[3] - mx);
    float inv = 1.f / (e0 + e1 + e2 + e3);
    aL[0][px] = e0 * inv; aL[1][px] = e1 * inv;
    aL[2][px] = e2 * inv; aL[3][px] = e3 * inv;
  }
  __syncthreads();

  // phase 2: per-(oc,px) output, coalesced along px
  for (int i = tid; i < 32 * HW; i += 384) {
    const int oc = i / HW;
    const int px = i - oc * HW;
    const int yy = px / 19, xx = px % 19;
    float acc = 0.f, aib = 0.f, a;
    if (yy > 0)  { a = aL[0][px]; acc += a * bf2f(Vl[oc][px - 19]); aib += a; }
    if (yy < 18) { a = aL[1][px]; acc += a * bf2f(Vl[oc][px + 19]); aib += a; }
    if (xx > 0)  { a = aL[2][px]; acc += a * bf2f(Vl[oc][px - 1]);  aib += a; }
    if (xx < 18) { a = aL[3][px]; acc += a * bf2f(Vl[oc][px + 1]);  aib += a; }
    float o = sl[64 + oc] * acc + tl[64 + oc] * aib;   // fold V-norm after sum
    o = fmaxf(o, 0.f);
    const size_t g = ((size_t)bb * 256 + h * 32 + oc) * HW + px;
    out[g] = o + x[g];
  }
}

// ---------------- workspace layout
constexpr size_t OFF_XT    = 0;
constexpr size_t SZ_XT     = (size_t)NPIX * 512;          // 94,633,984
constexpr size_t OFF_WALL  = OFF_XT + SZ_XT;
constexpr size_t SZ_WALL   = (size_t)NTOT * 512;          // 393,216
constexpr size_t OFF_BALL  = OFF_WALL + SZ_WALL;
constexpr size_t OFF_STATS = OFF_BALL + NTOT * 4;
constexpr size_t OFF_SALL  = OFF_STATS + 2 * NTOT * 4;
constexpr size_t OFF_TALL  = OFF_SALL + NTOT * 4;
constexpr size_t OFF_QKV   = OFF_TALL + NTOT * 4;
constexpr size_t WS_NEEDED = OFF_QKV + (size_t)NPIX * NTOT * 2;  // ~379 MB

extern "C" void kernel_launch(void* const* d_in, const int* in_sizes, int n_in,
                              void* d_out, int out_size, void* d_ws, size_t ws_size,
                              hipStream_t stream) {
  (void)in_sizes; (void)n_in; (void)out_size;
  if (ws_size < WS_NEEDED) return;   // insufficient scratch — bench will flag

  const float* x     = (const float*)d_in[0];
  const float* Wq    = (const float*)d_in[1];
  const float* bq    = (const float*)d_in[2];
  const float* Wk    = (const float*)d_in[3];
  const float* bk    = (const float*)d_in[4];
  const float* Wv    = (const float*)d_in[5];
  const float* bv    = (const float*)d_in[6];
  const float* gQ    = (const float*)d_in[7];
  const float* betaQ = (const float*)d_in[8];
  const float* gK    = (const float*)d_in[9];
  const float* betaK = (const float*)d_in[10];
  const float* gV    = (const float*)d_in[11];
  const float* betaV = (const float*)d_in[12];
  float* out = (float*)d_out;

  char* w = (char*)d_ws;
  u16*   xT    = (u16*)(w + OFF_XT);
  u16*   Wall  = (u16*)(w + OFF_WALL);
  float* ball  = (float*)(w + OFF_BALL);
  float* stats = (float*)(w + OFF_STATS);
  float* s_all = (float*)(w + OFF_SALL);
  float* t_all = (float*)(w + OFF_TALL);
  u16*   qkv   = (u16*)(w + OFF_QKV);

  k_prep<<<NTOT, 256, 0, stream>>>(Wq, bq, Wk, bk, Wv, bv, Wall, ball, stats);
  k_xt<<<NB, 384, 0, stream>>>(x, xT);
  k_gemm<<<NWG_M, 256, 0, stream>>>(xT, Wall, ball, qkv, stats);
  k_stats<<<1, NTOT, 0, stream>>>(stats, gQ, betaQ, gK, betaK, gV, betaV, s_all, t_all);
  k_attn<<<dim3(NB, NHEADS), 384, 0, stream>>>(qkv, s_all, t_all, x, out);
}

// Round 2
// 574.060 us; speedup vs baseline: 1.1406x; 1.1406x over previous
//
#include <hip/hip_runtime.h>

typedef unsigned short u16;
typedef unsigned int   u32;

#define NB     512
#define INC    256
#define NHEADS 8
#define HW     361
#define NPIX   184832      /* NB*HW */
#define NTOT   768
#define NWG_M  1444        /* NPIX/128 */
#define EPSBN  1e-5f

typedef __bf16 bf16x8 __attribute__((ext_vector_type(8)));
typedef float  f32x4  __attribute__((ext_vector_type(4)));

__device__ __forceinline__ u16 f2bf(float f) {
  u32 u = __float_as_uint(f);
  u += 0x7fffu + ((u >> 16) & 1u);          // round-to-nearest-even
  return (u16)(u >> 16);
}
__device__ __forceinline__ float bf2f(u16 v) {
  return __uint_as_float(((u32)v) << 16);
}

// ---------------- kernel 0: W -> bf16 [768][256] row-swizzled, bias, zero stats
__global__ __launch_bounds__(256) void k_prep(
    const float* __restrict__ Wq, const float* __restrict__ bq,
    const float* __restrict__ Wk, const float* __restrict__ bk,
    const float* __restrict__ Wv, const float* __restrict__ bv,
    u16* __restrict__ Wall, float* __restrict__ ball, float* __restrict__ stats) {
  const int n = blockIdx.x, t = threadIdx.x;
  const float* src; const float* bs; int r;
  if (n < 256)      { src = Wq; bs = bq; r = n; }
  else if (n < 512) { src = Wk; bs = bk; r = n - 256; }
  else              { src = Wv; bs = bv; r = n - 512; }
  float v = src[r * 256 + t];
  int byte = (t * 2) ^ ((n & 7) << 4);      // XOR swizzle, 16B granules (T2/G4)
  *(u16*)((char*)Wall + (size_t)n * 512 + byte) = f2bf(v);
  if (t == 0) ball[n] = bs[r];
  if (n == 0) { for (int i = t; i < 1536; i += 256) stats[i] = 0.f; }
}

// ---------------- kernel 0b: x [B][256][361] f32 -> xT [NPIX][256] bf16, row-swizzled
__global__ __launch_bounds__(384) void k_xt(const float* __restrict__ x, u16* __restrict__ xT) {
  const int bb = blockIdx.x, t = threadIdx.x;
  if (t >= HW) return;
  const size_t m = (size_t)bb * HW + t;
  const float* xp = x + (size_t)bb * INC * HW + t;
  char* dst = (char*)xT + m * 512;
  const int swz = ((int)m & 7) << 4;
  #pragma unroll 1
  for (int cc = 0; cc < INC; cc += 32) {
    __align__(16) u16 tmp[32];
    #pragma unroll
    for (int c = 0; c < 32; ++c) tmp[c] = f2bf(xp[(size_t)(cc + c) * HW]);
    #pragma unroll
    for (int p = 0; p < 4; ++p)
      *(uint4*)(dst + ((cc * 2 + p * 16) ^ swz)) = ((const uint4*)tmp)[p];
  }
}

// ---------------- kernel 1: QKV GEMM (M-tile 128, all 768 N, K=256) + stats epilogue
// outputs: qQ [bh][px][32c], qK/qV [bh][32c][px]  (attn-friendly layouts)
__global__ __launch_bounds__(256) void k_gemm(
    const u16* __restrict__ xT, const u16* __restrict__ Wall,
    const float* __restrict__ ball,
    u16* __restrict__ qQ, u16* __restrict__ qK, u16* __restrict__ qV,
    float* __restrict__ stats) {
  __shared__ u16 Al[128 * 256];                       // 64 KB, swizzled rows
  const int tid  = threadIdx.x;
  const int m0   = blockIdx.x * 128;
  {                                                   // stage A: contiguous 64 KB
    const uint4* src = (const uint4*)(xT + (size_t)m0 * 256);
    uint4* dst = (uint4*)Al;
    #pragma unroll
    for (int i = tid; i < 4096; i += 256) dst[i] = src[i];
  }
  __syncthreads();
  const int lane = tid & 63;
  const int w    = tid >> 6;
  const int wm   = w >> 1, wn = w & 1;
  const int l15  = lane & 15, kq = lane >> 4;
  const int swz  = (lane & 7) << 4;
  const char* Alb = (const char*)Al;
  const char* Wb  = (const char*)Wall;

  // precompute this thread's 16 output rows -> (bb,px) address bases
  int rQ[16], rKV[16];
  #pragma unroll
  for (int mi = 0; mi < 4; ++mi)
    #pragma unroll
    for (int j = 0; j < 4; ++j) {
      int m  = m0 + wm * 64 + mi * 16 + kq * 4 + j;
      int bb = m / 361;
      int px = m - bb * 361;
      rQ[mi * 4 + j]  = bb * 92416 + px * 32;   // (bb*8)*361*32 + px*32
      rKV[mi * 4 + j] = bb * 92416 + px;        // (bb*8)*32*361 + px
    }

  #pragma unroll 1
  for (int nt = 0; nt < 6; ++nt) {
    f32x4 acc[4][4];
    #pragma unroll
    for (int i = 0; i < 4; ++i)
      #pragma unroll
      for (int j = 0; j < 4; ++j) acc[i][j] = (f32x4){0.f, 0.f, 0.f, 0.f};
    const int nbase = nt * 128 + wn * 64;
    #pragma unroll
    for (int ks = 0; ks < 8; ++ks) {
      const int kb = kq * 16 + ks * 64;
      bf16x8 av[4], bvv[4];
      #pragma unroll
      for (int mi = 0; mi < 4; ++mi) {
        int r = wm * 64 + mi * 16 + l15;
        av[mi] = __builtin_bit_cast(bf16x8, *(const uint4*)(Alb + r * 512 + (kb ^ swz)));
      }
      #pragma unroll
      for (int ni = 0; ni < 4; ++ni) {
        int n = nbase + ni * 16 + l15;
        bvv[ni] = __builtin_bit_cast(bf16x8, *(const uint4*)(Wb + (size_t)n * 512 + (kb ^ swz)));
      }
      #pragma unroll
      for (int mi = 0; mi < 4; ++mi)
        #pragma unroll
        for (int ni = 0; ni < 4; ++ni)
          acc[mi][ni] = __builtin_amdgcn_mfma_f32_16x16x32_bf16(av[mi], bvv[ni], acc[mi][ni], 0, 0, 0);
    }
    const int which = nt >> 1;                      // 0=Q 1=K 2=V (uniform)
    // epilogue: bias, bf16 store (new layouts), per-channel sum/sumsq
    #pragma unroll
    for (int ni = 0; ni < 4; ++ni) {
      const int n    = nbase + ni * 16 + l15;
      const int ht   = ((n >> 5) & 7) * 11552;     // h * 32*361
      const int c    = n & 31;
      const int c361 = c * 361;
      const float bias = ball[n];
      float s = 0.f, sq = 0.f;
      #pragma unroll
      for (int mi = 0; mi < 4; ++mi) {
        #pragma unroll
        for (int j = 0; j < 4; ++j) {
          const int r = mi * 4 + j;
          float v = acc[mi][ni][j] + bias;
          u16 b16 = f2bf(v);
          if (which == 0)      qQ[rQ[r]  + ht + c]    = b16;
          else if (which == 1) qK[rKV[r] + ht + c361] = b16;
          else                 qV[rKV[r] + ht + c361] = b16;
          s += v; sq += v * v;
        }
      }
      s  += __shfl_down(s, 32);  sq += __shfl_down(sq, 32);
      s  += __shfl_down(s, 16);  sq += __shfl_down(sq, 16);
      if (kq == 0) {
        atomicAdd(&stats[n], s);
        atomicAdd(&stats[NTOT + n], sq);
      }
    }
  }
}

// ---------------- kernel 2: finalize BN -> s_all, t_all
__global__ void k_stats(const float* __restrict__ stats,
                        const float* __restrict__ gQ, const float* __restrict__ betaQ,
                        const float* __restrict__ gK, const float* __restrict__ betaK,
                        const float* __restrict__ gV, const float* __restrict__ betaV,
                        float* __restrict__ s_all, float* __restrict__ t_all) {
  const int n = threadIdx.x;
  if (n >= NTOT) return;
  const float invP = 1.f / (float)NPIX;
  float mean = stats[n] * invP;
  float var  = stats[NTOT + n] * invP - mean * mean;
  float g, be;
  if (n < 256)      { g = gQ[n];       be = betaQ[n]; }
  else if (n < 512) { g = gK[n - 256]; be = betaK[n - 256]; }
  else              { g = gV[n - 512]; be = betaV[n - 512]; }
  float s = g * rsqrtf(var + EPSBN);
  s_all[n] = s;
  t_all[n] = be - s * mean;
}

// ---------------- kernel 3: neighbor attention + softmax + ReLU + residual
// one block per (bb,h); K then V phase-share one 23KB LDS buffer
__global__ __launch_bounds__(384, 6) void k_attn(
    const u16* __restrict__ qQ, const u16* __restrict__ qK, const u16* __restrict__ qV,
    const float* __restrict__ s_all, const float* __restrict__ t_all,
    const float* __restrict__ x, float* __restrict__ out) {
  __shared__ __align__(16) u16 KV[32 * HW];          // 23104 B, [c][px]
  __shared__ float sQ[32], tQ[32], sK[32], tK[32], sV[32], tV[32];
  const int bb = blockIdx.x, h = blockIdx.y, tid = threadIdx.x;
  const int bh = bb * NHEADS + h;

  if (tid < 96) {
    int which = tid >> 5, c = tid & 31;
    float sv = s_all[which * 256 + h * 32 + c];
    float tv = t_all[which * 256 + h * 32 + c];
    if (which == 0)      { sQ[c] = sv; tQ[c] = tv; }
    else if (which == 1) { sK[c] = sv; tK[c] = tv; }
    else                 { sV[c] = sv; tV[c] = tv; }
  }
  // stage K: flat coalesced copy (1444 uint4)
  uint4* kvv = (uint4*)KV;
  {
    const uint4* gk = (const uint4*)(qK + (size_t)bh * 11552);
    for (int i = tid; i < 1444; i += 384) kvv[i] = gk[i];
  }
  __syncthreads();

  const int px = tid;
  const bool act = tid < HW;
  float a0 = 0.f, a1 = 0.f, a2 = 0.f, a3 = 0.f;
  int pn0 = 0, pn1 = 0, pn2 = 0, pn3 = 0;
  if (act) {
    const int yy = px / 19, xx = px - yy * 19;
    const bool i0 = yy > 0, i1 = yy < 18, i2 = xx > 0, i3 = xx < 18;
    pn0 = i0 ? px - 19 : px;  pn1 = i1 ? px + 19 : px;
    pn2 = i2 ? px - 1  : px;  pn3 = i3 ? px + 1  : px;
    const u16* K0 = KV + pn0; const u16* K1 = KV + pn1;
    const u16* K2 = KV + pn2; const u16* K3 = KV + pn3;
    const uint4* q4 = (const uint4*)(qQ + ((size_t)bh * HW + px) * 32);
    uint4 qA = q4[0], qB = q4[1], qC = q4[2], qD = q4[3];
    float d0 = 0.f, d1 = 0.f, d2 = 0.f, d3 = 0.f, Ct = 0.f;
#define CH2(wrd, c0) { \
    float ql = bf2f((u16)((wrd) & 0xffffu)), qh = bf2f((u16)((wrd) >> 16)); \
    float qn0 = sQ[c0] * ql + tQ[c0]; \
    float qn1 = sQ[(c0)+1] * qh + tQ[(c0)+1]; \
    Ct += qn0 * tK[c0] + qn1 * tK[(c0)+1]; \
    float w0 = qn0 * sK[c0], w1 = qn1 * sK[(c0)+1]; \
    d0 += w0 * bf2f(K0[(c0)*HW]) + w1 * bf2f(K0[((c0)+1)*HW]); \
    d1 += w0 * bf2f(K1[(c0)*HW]) + w1 * bf2f(K1[((c0)+1)*HW]); \
    d2 += w0 * bf2f(K2[(c0)*HW]) + w1 * bf2f(K2[((c0)+1)*HW]); \
    d3 += w0 * bf2f(K3[(c0)*HW]) + w1 * bf2f(K3[((c0)+1)*HW]); \
  }
    CH2(qA.x, 0)  CH2(qA.y, 2)  CH2(qA.z, 4)  CH2(qA.w, 6)
    CH2(qB.x, 8)  CH2(qB.y, 10) CH2(qB.z, 12) CH2(qB.w, 14)
    CH2(qC.x, 16) CH2(qC.y, 18) CH2(qC.z, 20) CH2(qC.w, 22)
    CH2(qD.x, 24) CH2(qD.y, 26) CH2(qD.z, 28) CH2(qD.w, 30)
#undef CH2
    const float rs = 0.17677669529663687f;     // 1/sqrt(32)
    float l0 = i0 ? (d0 + Ct) * rs : 0.f;
    float l1 = i1 ? (d1 + Ct) * rs : 0.f;
    float l2 = i2 ? (d2 + Ct) * rs : 0.f;
    float l3 = i3 ? (d3 + Ct) * rs : 0.f;
    float mx = fmaxf(fmaxf(l0, l1), fmaxf(l2, l3));
    float e0 = __expf(l0 - mx), e1 = __expf(l1 - mx);
    float e2 = __expf(l2 - mx), e3 = __expf(l3 - mx);
    float inv = 1.f / (e0 + e1 + e2 + e3);
    a0 = i0 ? e0 * inv : 0.f;  a1 = i1 ? e1 * inv : 0.f;
    a2 = i2 ? e2 * inv : 0.f;  a3 = i3 ? e3 * inv : 0.f;
  }
  __syncthreads();
  // stage V over the same buffer
  {
    const uint4* gv = (const uint4*)(qV + (size_t)bh * 11552);
    for (int i = tid; i < 1444; i += 384) kvv[i] = gv[i];
  }
  __syncthreads();

  if (act) {
    const float ai = a0 + a1 + a2 + a3;
    const u16* V0 = KV + pn0; const u16* V1 = KV + pn1;
    const u16* V2 = KV + pn2; const u16* V3 = KV + pn3;
    const size_t gb = ((size_t)bb * 256 + h * 32) * HW + px;
    #pragma unroll
    for (int oc = 0; oc < 32; ++oc) {
      float v = a0 * bf2f(V0[oc * HW]) + a1 * bf2f(V1[oc * HW])
              + a2 * bf2f(V2[oc * HW]) + a3 * bf2f(V3[oc * HW]);
      float o = sV[oc] * v + tV[oc] * ai;
      o = fmaxf(o, 0.f);
      const size_t g = gb + (size_t)oc * HW;
      out[g] = o + x[g];
    }
  }
}

// ---------------- workspace layout
constexpr size_t OFF_XT    = 0;
constexpr size_t SZ_XT     = (size_t)NPIX * 512;          // 94,633,984
constexpr size_t OFF_WALL  = OFF_XT + SZ_XT;
constexpr size_t SZ_WALL   = (size_t)NTOT * 512;
constexpr size_t OFF_BALL  = OFF_WALL + SZ_WALL;
constexpr size_t OFF_STATS = OFF_BALL + NTOT * 4;
constexpr size_t OFF_SALL  = OFF_STATS + 2 * NTOT * 4;
constexpr size_t OFF_TALL  = OFF_SALL + NTOT * 4;
constexpr size_t OFF_QQ    = OFF_TALL + NTOT * 4;
constexpr size_t SZ_ONE    = (size_t)NPIX * 256 * 2;      // 94,633,984 each
constexpr size_t OFF_QK    = OFF_QQ + SZ_ONE;
constexpr size_t OFF_QV    = OFF_QK + SZ_ONE;
constexpr size_t WS_NEEDED = OFF_QV + SZ_ONE;             // ~379 MB

extern "C" void kernel_launch(void* const* d_in, const int* in_sizes, int n_in,
                              void* d_out, int out_size, void* d_ws, size_t ws_size,
                              hipStream_t stream) {
  (void)in_sizes; (void)n_in; (void)out_size;
  if (ws_size < WS_NEEDED) return;

  const float* x     = (const float*)d_in[0];
  const float* Wq    = (const float*)d_in[1];
  const float* bq    = (const float*)d_in[2];
  const float* Wk    = (const float*)d_in[3];
  const float* bk    = (const float*)d_in[4];
  const float* Wv    = (const float*)d_in[5];
  const float* bv    = (const float*)d_in[6];
  const float* gQ    = (const float*)d_in[7];
  const float* betaQ = (const float*)d_in[8];
  const float* gK    = (const float*)d_in[9];
  const float* betaK = (const float*)d_in[10];
  const float* gV    = (const float*)d_in[11];
  const float* betaV = (const float*)d_in[12];
  float* out = (float*)d_out;

  char* w = (char*)d_ws;
  u16*   xT    = (u16*)(w + OFF_XT);
  u16*   Wall  = (u16*)(w + OFF_WALL);
  float* ball  = (float*)(w + OFF_BALL);
  float* stats = (float*)(w + OFF_STATS);
  float* s_all = (float*)(w + OFF_SALL);
  float* t_all = (float*)(w + OFF_TALL);
  u16*   qQ    = (u16*)(w + OFF_QQ);
  u16*   qK    = (u16*)(w + OFF_QK);
  u16*   qV    = (u16*)(w + OFF_QV);

  k_prep<<<NTOT, 256, 0, stream>>>(Wq, bq, Wk, bk, Wv, bv, Wall, ball, stats);
  k_xt<<<NB, 384, 0, stream>>>(x, xT);
  k_gemm<<<NWG_M, 256, 0, stream>>>(xT, Wall, ball, qQ, qK, qV, stats);
  k_stats<<<1, NTOT, 0, stream>>>(stats, gQ, betaQ, gK, betaK, gV, betaV, s_all, t_all);
  k_attn<<<dim3(NB, NHEADS), 384, 0, stream>>>(qQ, qK, qV, s_all, t_all, x, out);
}